// Round 7
// baseline (382.882 us; speedup 1.0000x reference)
//
#include <hip/hip_runtime.h>
#include <hip/hip_bf16.h>
#include <stdint.h>

typedef uint16_t u16;
typedef uint32_t u32;
typedef __attribute__((ext_vector_type(8))) short bv8;    // 8 x bf16 (i16 bits), 4 VGPR
typedef __attribute__((ext_vector_type(4))) float f32x4;
typedef __attribute__((ext_vector_type(2))) u32 u32x2;

#define MFMA(a,b,c) __builtin_amdgcn_mfma_f32_16x16x32_bf16((a),(b),(c),0,0,0)

__device__ __forceinline__ float bf2f(u16 v){ u32 x=(u32)v<<16; float f; __builtin_memcpy(&f,&x,4); return f; }
__device__ __forceinline__ u16 f2bf(float f){ u32 x; __builtin_memcpy(&x,&f,4); x += 0x7fffu + ((x>>16)&1u); return (u16)(x>>16); }
__device__ __forceinline__ u32 cvtpk_bf16(float lo, float hi){
  u32 r; asm("v_cvt_pk_bf16_f32 %0, %1, %2" : "=v"(r) : "v"(lo), "v"(hi)); return r;
}
__device__ __forceinline__ float exp2_fast(float x){
  float r; asm("v_exp_f32 %0, %1" : "=v"(r) : "v"(x)); return r;
}

__device__ __forceinline__ void gl_lds16(const u16* g, u16* l){
  __builtin_amdgcn_global_load_lds((const __attribute__((address_space(1))) u32*)g,
                                   (__attribute__((address_space(3))) u32*)l, 16, 0, 0);
}

// fp32 -> bf16 convert. n8 = elements/8.
__global__ __launch_bounds__(256) void cvt_bf16(const float* __restrict__ src, u16* __restrict__ dst, long n8){
  long i = (long)blockIdx.x*256 + threadIdx.x;
  long stride = (long)gridDim.x*256;
  for(; i<n8; i+=stride){
    f32x4 a = *(const f32x4*)(src + i*8);
    f32x4 b = *(const f32x4*)(src + i*8 + 4);
    bv8 o;
    #pragma unroll
    for(int j=0;j<4;j++) o[j]   = (short)f2bf(a[j]);
    #pragma unroll
    for(int j=0;j<4;j++) o[4+j] = (short)f2bf(b[j]);
    *(bv8*)(dst + i*8) = o;
  }
}

// ---------------------------------------------------------------------------
// C[m,n] = sum_k A[m,k] * B[n,k]   (A: MxK bf16 row-major, B: NxK bf16)
// 128x128 tile, BK=64, 4 waves, global_load_lds w/ pre-swizzled src.
// ---------------------------------------------------------------------------
template<bool OUTF32>
__global__ __launch_bounds__(256,2) void gemm_bt(const u16* __restrict__ A, const u16* __restrict__ B,
                                                 void* __restrict__ Cv, int M, int N, int K){
  __shared__ __align__(16) u16 As[128*64];
  __shared__ __align__(16) u16 Bs[128*64];
  int nwg = gridDim.x;
  int wg  = (int)blockIdx.x;
  wg = (wg & 7)*(nwg>>3) + (wg>>3);          // XCD swizzle (nwg % 8 == 0)
  int nn = N>>7;
  int tm = wg/nn, tn = wg - tm*nn;
  int rowbase = tm<<7, colbase = tn<<7;
  int t = threadIdx.x, lane = t&63, w = t>>6;
  int g = lane>>4, q16 = lane&15;
  int wr = w>>1, wc = w&1;

  f32x4 z = {0.f,0.f,0.f,0.f};
  f32x4 acc[4][4];
  #pragma unroll
  for(int i=0;i<4;i++)
    #pragma unroll
    for(int j=0;j<4;j++) acc[i][j]=z;

  for(int k0=0;k0<K;k0+=64){
    __syncthreads();
    #pragma unroll
    for(int i=0;i<4;i++){
      int s = ((w<<2)+i)*64 + lane;
      int row = s>>3;
      int ksl = (s&7) ^ (row&7);
      gl_lds16(A + (size_t)(rowbase+row)*K + k0 + ksl*8, (u16*)As + ((w<<2)+i)*512);
      gl_lds16(B + (size_t)(colbase+row)*K + k0 + ksl*8, (u16*)Bs + ((w<<2)+i)*512);
    }
    __syncthreads();
    #pragma unroll
    for(int eks=0;eks<2;eks++){
      bv8 af[4], bfr[4];
      #pragma unroll
      for(int mi=0;mi<4;mi++){
        int row = (wr<<6)+(mi<<4)+q16;
        af[mi] = *(const bv8*)(As + row*64 + ((((eks<<2)|g) ^ (row&7))<<3));
      }
      #pragma unroll
      for(int ni=0;ni<4;ni++){
        int row = (wc<<6)+(ni<<4)+q16;
        bfr[ni] = *(const bv8*)(Bs + row*64 + ((((eks<<2)|g) ^ (row&7))<<3));
      }
      #pragma unroll
      for(int mi=0;mi<4;mi++)
        #pragma unroll
        for(int ni=0;ni<4;ni++)
          acc[mi][ni] = MFMA(af[mi], bfr[ni], acc[mi][ni]);
    }
  }
  #pragma unroll
  for(int mi=0;mi<4;mi++){
    #pragma unroll
    for(int ni=0;ni<4;ni++){
      int row = rowbase + (wr<<6) + (mi<<4) + (g<<2);
      int col = colbase + (wc<<6) + (ni<<4) + q16;
      if(OUTF32){
        float* cp = (float*)Cv + (size_t)row*N + col;
        #pragma unroll
        for(int r=0;r<4;r++) cp[(size_t)r*N] = acc[mi][ni][r];
      } else {
        u16* cp = (u16*)Cv + (size_t)row*N + col;
        #pragma unroll
        for(int r=0;r<4;r++) cp[(size_t)r*N] = f2bf(acc[mi][ni][r]);
      }
    }
  }
}

// ---------------------------------------------------------------------------
// In-place RMSNorm + RoPE on q,k of qkv. One wave per row of 64.
// q rows scaled by (1/8)*log2(e): softmax scale + exp2-domain fold.
// ---------------------------------------------------------------------------
__global__ __launch_bounds__(256) void normrope(u16* __restrict__ qkv, const float* __restrict__ cosT,
                                                const float* __restrict__ sinT, const float* __restrict__ qw,
                                                const float* __restrict__ kw){
  int t = threadIdx.x, lane = t&63, wv = t>>6;
  long gid = (long)blockIdx.x*4 + wv;        // over B*L*2*H = 262144 rows
  int h = (int)(gid & 15);
  int s = (int)((gid>>4) & 1);
  long bl = gid >> 5;                        // 0..8191
  int l = (int)(bl & 1023);
  u16* p = qkv + bl*3072 + s*1024 + h*64 + lane;
  float x = bf2f(*p);
  float ss = x*x;
  #pragma unroll
  for(int m=1;m<64;m<<=1) ss += __shfl_xor(ss, m, 64);
  float nrm = rsqrtf(ss*(1.f/64.f) + 1e-6f);
  float y = x * nrm * (s ? kw[lane] : qw[lane]);
  float other = __shfl_xor(y, 32, 64);
  float rot = (lane<32)? -other : other;     // rotate_half
  int ci = l*64 + lane;
  float outv = y*cosT[ci] + rot*sinT[ci];
  *p = f2bf(s ? outv : outv*0.1803368801111437f);   // 0.125 * log2(e)
}

// ---------------------------------------------------------------------------
// Flash attention. 8 waves x 16 q-rows (BQ=128), KV tile 128.
// K double-buffered via global_load_lds DMA (pre-swizzled src, conflict-free
// reads). V^T single-buffer in LDS (row=d 256B, slot^=(d&15), conflict-free
// reads), reg-staged by waves 0-3. 2 barriers/tile. Softmax in exp2 domain.
// P->PV A-frag redistribution via validated cvt_pk + __shfl network (R3/R4).
// ---------------------------------------------------------------------------
__global__ __launch_bounds__(512,6) void fattn(const u16* __restrict__ qkv, u16* __restrict__ Out){
  __shared__ __align__(16) u16 Ks0[128*64];     // 16KB [kv][e], slot^=(kv&7)
  __shared__ __align__(16) u16 Ks1[128*64];     // 16KB
  __shared__ __align__(16) u16 Vt[64*128];      // 16KB [d][kv], slot^=(d&15)

  int t = threadIdx.x, lane = t&63, w = t>>6;   // w in 0..7
  int g = lane>>4, q16 = lane&15;
  int nwg = gridDim.x;
  int bid = (int)blockIdx.x;
  bid = (bid & 7)*(nwg>>3) + (bid>>3);          // XCD swizzle (nwg=1024, %8==0)
  int bh = bid >> 3, qt = bid & 7;              // 8 q-tiles of 128 rows
  int b = bh >> 4, h = bh & 15;
  const u16* base = qkv + (size_t)b*1024*3072;

  bv8 qf[2];
  {
    const u16* qp = base + (size_t)((qt<<7) + (w<<4) + q16)*3072 + h*64;
    qf[0] = *(const bv8*)(qp + (g<<3));
    qf[1] = *(const bv8*)(qp + 32 + (g<<3));
  }
  f32x4 z = {0.f,0.f,0.f,0.f};
  f32x4 accO[4];
  #pragma unroll
  for(int i=0;i<4;i++) accO[i]=z;
  float m_run = -1e30f, l_run = 0.f;

  // V staging geometry (threads 0..255 only): kv rows [kvr,kvr+4) x d [d0v,d0v+8)
  bool vstage = (t < 256);
  int d0v = (t&7)<<3;
  int c4  = (t>>3)&31;
  int sV = c4>>1, halfV = c4&1, kvr = c4<<2;
  int d15b = (t&1)<<3;

  // P-redistribution shuffle constants (validated R3/R4)
  int sel = g>>1;
  int s0l = (((g<<1)&3)<<4) | q16;
  int s1l = s0l + 16;

  bv8 v0,v1,v2,v3;
  const u16* gV0 = base + (size_t)kvr*3072 + 2048 + h*64 + d0v;

#define LDV(tl) if(vstage){ const u16* gV = gV0 + (size_t)(tl)*393216; \
    v0 = *(const bv8*)(gV);       v1 = *(const bv8*)(gV+3072); \
    v2 = *(const bv8*)(gV+6144);  v3 = *(const bv8*)(gV+9216); }

#define STV() if(vstage){ \
    _Pragma("unroll") \
    for(int i=0;i<8;i++){ \
      int d = d0v + i; \
      u32x2 val; \
      val.x = (u32)(u16)v0[i] | ((u32)(u16)v1[i]<<16); \
      val.y = (u32)(u16)v2[i] | ((u32)(u16)v3[i]<<16); \
      *(u32x2*)(Vt + d*128 + (((sV ^ (d15b+i))<<3) + (halfV<<2))) = val; \
    } }

#define KDMA(tl, buf) { \
    _Pragma("unroll") \
    for(int i=0;i<2;i++){ \
      int si = ((w<<1)+i)*64 + lane; \
      int row = si>>3; \
      int esl = (si&7) ^ (row&7); \
      gl_lds16(base + (size_t)(((tl)<<7)+row)*3072 + 1024 + h*64 + esl*8, (buf) + ((w<<1)+i)*512); \
    } }

  // prologue: K(0) DMA, V(0) regs
  KDMA(0, (u16*)Ks0);
  LDV(0);

  for(int tile=0; tile<8; ++tile){
    u16* kcur = (tile&1) ? (u16*)Ks1 : (u16*)Ks0;
    u16* knxt = (tile&1) ? (u16*)Ks0 : (u16*)Ks1;
    if(tile>0) __syncthreads();     // sync_A: all waves done reading Vt & knxt
    STV();                          // write V(tile)
    __syncthreads();                // sync_B: Vt visible; K(tile) DMA drained
    if(tile<7){
      KDMA(tile+1, knxt);           // DMA overlaps this tile's compute
      LDV(tile+1);                  // regs for next STV
    }

    // QK^T (swapped): sacc[mi] = S^T[kv=16mi+4g+r][q16], log2-domain
    f32x4 sacc[8];
    #pragma unroll
    for(int i=0;i<8;i++) sacc[i]=z;
    bv8 kf[8];
    #pragma unroll
    for(int mi=0;mi<8;mi++){
      int row = (mi<<4) + q16;
      kf[mi] = *(const bv8*)(kcur + row*64 + ((g ^ (row&7))<<3));
    }
    __builtin_amdgcn_s_setprio(1);
    #pragma unroll
    for(int mi=0;mi<8;mi++) sacc[mi] = MFMA(kf[mi], qf[0], sacc[mi]);
    __builtin_amdgcn_s_setprio(0);
    #pragma unroll
    for(int mi=0;mi<8;mi++){
      int row = (mi<<4) + q16;
      kf[mi] = *(const bv8*)(kcur + row*64 + (((4|g) ^ (row&7))<<3));
    }
    __builtin_amdgcn_s_setprio(1);
    #pragma unroll
    for(int mi=0;mi<8;mi++) sacc[mi] = MFMA(kf[mi], qf[1], sacc[mi]);
    __builtin_amdgcn_s_setprio(0);

    // online softmax in exp2 domain (per q-row = q16; replicas lane^16,^32)
    float rm = -1e30f;
    #pragma unroll
    for(int mi=0;mi<8;mi++){
      float a = fmaxf(sacc[mi][0], sacc[mi][1]);
      float c = fmaxf(sacc[mi][2], sacc[mi][3]);
      rm = fmaxf(rm, fmaxf(a, c));
    }
    rm = fmaxf(rm, __shfl_xor(rm,16,64));
    rm = fmaxf(rm, __shfl_xor(rm,32,64));
    float mnew = fmaxf(m_run, rm);
    float fac = exp2_fast(m_run - mnew);
    m_run = mnew;
    float ps = 0.f;
    #pragma unroll
    for(int mi=0;mi<8;mi++)
      #pragma unroll
      for(int r=0;r<4;r++){
        float p = exp2_fast(sacc[mi][r]-mnew);
        sacc[mi][r] = p;
        ps += p;
      }
    ps += __shfl_xor(ps,16,64);
    ps += __shfl_xor(ps,32,64);
    l_run = l_run*fac + ps;
    float fr0 = __shfl(fac, (g<<2)|0, 64);
    float fr1 = __shfl(fac, (g<<2)|1, 64);
    float fr2 = __shfl(fac, (g<<2)|2, 64);
    float fr3 = __shfl(fac, (g<<2)|3, 64);
    #pragma unroll
    for(int db=0;db<4;db++){ accO[db][0]*=fr0; accO[db][1]*=fr1; accO[db][2]*=fr2; accO[db][3]*=fr3; }

    // PV: pf via cvt_pk + validated shuffle network, vf from swizzled Vt
    #pragma unroll
    for(int ks=0;ks<4;ks++){
      u32 A0 = cvtpk_bf16(sacc[2*ks][0],   sacc[2*ks][1]);
      u32 A1 = cvtpk_bf16(sacc[2*ks][2],   sacc[2*ks][3]);
      u32 B0 = cvtpk_bf16(sacc[2*ks+1][0], sacc[2*ks+1][1]);
      u32 B1 = cvtpk_bf16(sacc[2*ks+1][2], sacc[2*ks+1][3]);
      u32 wA0 = (u32)__shfl((int)A0, s0l, 64), wB0 = (u32)__shfl((int)B0, s0l, 64);
      u32 wA1 = (u32)__shfl((int)A1, s0l, 64), wB1 = (u32)__shfl((int)B1, s0l, 64);
      u32 xA0 = (u32)__shfl((int)A0, s1l, 64), xB0 = (u32)__shfl((int)B0, s1l, 64);
      u32 xA1 = (u32)__shfl((int)A1, s1l, 64), xB1 = (u32)__shfl((int)B1, s1l, 64);
      union { u32 u[4]; bv8 v; } pfu;
      pfu.u[0] = sel ? wB0 : wA0;
      pfu.u[1] = sel ? wB1 : wA1;
      pfu.u[2] = sel ? xB0 : xA0;
      pfu.u[3] = sel ? xB1 : xA1;
      int fbase = ((ks<<2)|g) ^ q16;
      __builtin_amdgcn_s_setprio(1);
      #pragma unroll
      for(int db=0;db<4;db++){
        int dd = (db<<4) + q16;
        bv8 vf = *(const bv8*)(Vt + dd*128 + (fbase<<3));
        accO[db] = MFMA(pfu.v, vf, accO[db]);
      }
      __builtin_amdgcn_s_setprio(0);
    }
  }
  // epilogue
  float li0 = 1.f/__shfl(l_run, (g<<2)|0, 64);
  float li1 = 1.f/__shfl(l_run, (g<<2)|1, 64);
  float li2 = 1.f/__shfl(l_run, (g<<2)|2, 64);
  float li3 = 1.f/__shfl(l_run, (g<<2)|3, 64);
  #pragma unroll
  for(int db=0;db<4;db++){
    int qrow = (qt<<7) + (w<<4) + (g<<2);
    size_t o = (size_t)(b*1024 + qrow)*1024 + h*64 + (db<<4) + q16;
    Out[o        ] = f2bf(accO[db][0]*li0);
    Out[o + 1024 ] = f2bf(accO[db][1]*li1);
    Out[o + 2048 ] = f2bf(accO[db][2]*li2);
    Out[o + 3072 ] = f2bf(accO[db][3]*li3);
  }
#undef LDV
#undef STV
#undef KDMA
}

extern "C" void kernel_launch(void* const* d_in, const int* in_sizes, int n_in,
                              void* d_out, int out_size, void* d_ws, size_t ws_size,
                              hipStream_t stream) {
  const float* x      = (const float*)d_in[0];
  const float* cosT   = (const float*)d_in[1];
  const float* sinT   = (const float*)d_in[2];
  const float* w_qkv  = (const float*)d_in[3];
  const float* w_proj = (const float*)d_in[4];
  const float* qw     = (const float*)d_in[5];
  const float* kw     = (const float*)d_in[6];
  float* out = (float*)d_out;

  // ws layout (u16 units): xb dead after qkv GEMM -> attn aliases it.
  u16* xb     = (u16*)d_ws;                         //  8388608 elems
  u16* wqkvb  = xb     + (size_t) 8388608;          //  3145728
  u16* wprojb = wqkvb  + (size_t) 3145728;          //  1048576
  u16* qkv    = wprojb + (size_t) 1048576;          // 25165824
  u16* attn   = xb;                                 //  8388608 (alias)

  cvt_bf16<<<2048, 256, 0, stream>>>(x,      xb,     1048576);
  cvt_bf16<<<1536, 256, 0, stream>>>(w_qkv,  wqkvb,   393216);
  cvt_bf16<<< 512, 256, 0, stream>>>(w_proj, wprojb,  131072);

  gemm_bt<false><<<1536, 256, 0, stream>>>(xb, wqkvb, qkv, 8192, 3072, 1024);
  normrope<<<65536, 256, 0, stream>>>(qkv, cosT, sinT, qw, kw);
  fattn   <<<1024, 512, 0, stream>>>(qkv, attn);
  gemm_bt<true><<<512, 256, 0, stream>>>(attn, wprojb, out, 8192, 1024, 1024);
}

// Round 8
// 239.904 us; speedup vs baseline: 1.5960x; 1.5960x over previous
//
#include <hip/hip_runtime.h>
#include <hip/hip_bf16.h>
#include <stdint.h>

typedef uint16_t u16;
typedef uint32_t u32;
typedef __attribute__((ext_vector_type(8))) short bv8;    // 8 x bf16 (i16 bits), 4 VGPR
typedef __attribute__((ext_vector_type(4))) float f32x4;
typedef __attribute__((ext_vector_type(2))) u32 u32x2;

#define MFMA(a,b,c) __builtin_amdgcn_mfma_f32_16x16x32_bf16((a),(b),(c),0,0,0)

__device__ __forceinline__ float bf2f(u16 v){ u32 x=(u32)v<<16; float f; __builtin_memcpy(&f,&x,4); return f; }
__device__ __forceinline__ u16 f2bf(float f){ u32 x; __builtin_memcpy(&x,&f,4); x += 0x7fffu + ((x>>16)&1u); return (u16)(x>>16); }
__device__ __forceinline__ u32 cvtpk_bf16(float lo, float hi){
  u32 r; asm("v_cvt_pk_bf16_f32 %0, %1, %2" : "=v"(r) : "v"(lo), "v"(hi)); return r;
}
__device__ __forceinline__ float exp2_fast(float x){
  float r; asm("v_exp_f32 %0, %1" : "=v"(r) : "v"(x)); return r;
}

__device__ __forceinline__ void gl_lds16(const u16* g, u16* l){
  __builtin_amdgcn_global_load_lds((const __attribute__((address_space(1))) u32*)g,
                                   (__attribute__((address_space(3))) u32*)l, 16, 0, 0);
}

// fp32 -> bf16 convert. n8 = elements/8.
__global__ __launch_bounds__(256) void cvt_bf16(const float* __restrict__ src, u16* __restrict__ dst, long n8){
  long i = (long)blockIdx.x*256 + threadIdx.x;
  long stride = (long)gridDim.x*256;
  for(; i<n8; i+=stride){
    f32x4 a = *(const f32x4*)(src + i*8);
    f32x4 b = *(const f32x4*)(src + i*8 + 4);
    bv8 o;
    #pragma unroll
    for(int j=0;j<4;j++) o[j]   = (short)f2bf(a[j]);
    #pragma unroll
    for(int j=0;j<4;j++) o[4+j] = (short)f2bf(b[j]);
    *(bv8*)(dst + i*8) = o;
  }
}

// ---------------------------------------------------------------------------
// C[m,n] = sum_k A[m,k] * B[n,k]   (A: MxK bf16 row-major, B: NxK bf16)
// 128x128 tile, BK=64, 4 waves, global_load_lds w/ pre-swizzled src.
// ---------------------------------------------------------------------------
template<bool OUTF32>
__global__ __launch_bounds__(256,2) void gemm_bt(const u16* __restrict__ A, const u16* __restrict__ B,
                                                 void* __restrict__ Cv, int M, int N, int K){
  __shared__ __align__(16) u16 As[128*64];
  __shared__ __align__(16) u16 Bs[128*64];
  int nwg = gridDim.x;
  int wg  = (int)blockIdx.x;
  wg = (wg & 7)*(nwg>>3) + (wg>>3);          // XCD swizzle (nwg % 8 == 0)
  int nn = N>>7;
  int tm = wg/nn, tn = wg - tm*nn;
  int rowbase = tm<<7, colbase = tn<<7;
  int t = threadIdx.x, lane = t&63, w = t>>6;
  int g = lane>>4, q16 = lane&15;
  int wr = w>>1, wc = w&1;

  f32x4 z = {0.f,0.f,0.f,0.f};
  f32x4 acc[4][4];
  #pragma unroll
  for(int i=0;i<4;i++)
    #pragma unroll
    for(int j=0;j<4;j++) acc[i][j]=z;

  for(int k0=0;k0<K;k0+=64){
    __syncthreads();
    #pragma unroll
    for(int i=0;i<4;i++){
      int s = ((w<<2)+i)*64 + lane;
      int row = s>>3;
      int ksl = (s&7) ^ (row&7);
      gl_lds16(A + (size_t)(rowbase+row)*K + k0 + ksl*8, (u16*)As + ((w<<2)+i)*512);
      gl_lds16(B + (size_t)(colbase+row)*K + k0 + ksl*8, (u16*)Bs + ((w<<2)+i)*512);
    }
    __syncthreads();
    #pragma unroll
    for(int eks=0;eks<2;eks++){
      bv8 af[4], bfr[4];
      #pragma unroll
      for(int mi=0;mi<4;mi++){
        int row = (wr<<6)+(mi<<4)+q16;
        af[mi] = *(const bv8*)(As + row*64 + ((((eks<<2)|g) ^ (row&7))<<3));
      }
      #pragma unroll
      for(int ni=0;ni<4;ni++){
        int row = (wc<<6)+(ni<<4)+q16;
        bfr[ni] = *(const bv8*)(Bs + row*64 + ((((eks<<2)|g) ^ (row&7))<<3));
      }
      #pragma unroll
      for(int mi=0;mi<4;mi++)
        #pragma unroll
        for(int ni=0;ni<4;ni++)
          acc[mi][ni] = MFMA(af[mi], bfr[ni], acc[mi][ni]);
    }
  }
  #pragma unroll
  for(int mi=0;mi<4;mi++){
    #pragma unroll
    for(int ni=0;ni<4;ni++){
      int row = rowbase + (wr<<6) + (mi<<4) + (g<<2);
      int col = colbase + (wc<<6) + (ni<<4) + q16;
      if(OUTF32){
        float* cp = (float*)Cv + (size_t)row*N + col;
        #pragma unroll
        for(int r=0;r<4;r++) cp[(size_t)r*N] = acc[mi][ni][r];
      } else {
        u16* cp = (u16*)Cv + (size_t)row*N + col;
        #pragma unroll
        for(int r=0;r<4;r++) cp[(size_t)r*N] = f2bf(acc[mi][ni][r]);
      }
    }
  }
}

// ---------------------------------------------------------------------------
// In-place RMSNorm + RoPE on q,k of qkv. One wave per row of 64.
// q rows scaled by (1/8)*log2(e): softmax scale + exp2-domain fold.
// ---------------------------------------------------------------------------
__global__ __launch_bounds__(256) void normrope(u16* __restrict__ qkv, const float* __restrict__ cosT,
                                                const float* __restrict__ sinT, const float* __restrict__ qw,
                                                const float* __restrict__ kw){
  int t = threadIdx.x, lane = t&63, wv = t>>6;
  long gid = (long)blockIdx.x*4 + wv;        // over B*L*2*H = 262144 rows
  int h = (int)(gid & 15);
  int s = (int)((gid>>4) & 1);
  long bl = gid >> 5;                        // 0..8191
  int l = (int)(bl & 1023);
  u16* p = qkv + bl*3072 + s*1024 + h*64 + lane;
  float x = bf2f(*p);
  float ss = x*x;
  #pragma unroll
  for(int m=1;m<64;m<<=1) ss += __shfl_xor(ss, m, 64);
  float nrm = rsqrtf(ss*(1.f/64.f) + 1e-6f);
  float y = x * nrm * (s ? kw[lane] : qw[lane]);
  float other = __shfl_xor(y, 32, 64);
  float rot = (lane<32)? -other : other;     // rotate_half
  int ci = l*64 + lane;
  float outv = y*cosT[ci] + rot*sinT[ci];
  *p = f2bf(s ? outv : outv*0.1803368801111437f);   // 0.125 * log2(e)
}

// ---------------------------------------------------------------------------
// Flash attention. 4 waves x 16 q-rows (BQ=64), KV tile 128.
// K double-buffered via global_load_lds DMA (pre-swizzled src, conflict-free
// reads). V^T single-buffer in LDS (row=d 256B, slot^=(d&15), conflict-free
// reads), reg-staged. 2 barriers/tile. Softmax in exp2 domain with defer-max
// (skip rescale when per-tile max grows < 8 log2 units; bf16 P bounded 256).
// P->PV A-frag redistribution via validated cvt_pk + __shfl network (R3/R4).
// ---------------------------------------------------------------------------
__global__ __launch_bounds__(256,3) void fattn(const u16* __restrict__ qkv, u16* __restrict__ Out){
  __shared__ __align__(16) u16 Ks0[128*64];     // 16KB [kv][e], slot^=(kv&7)
  __shared__ __align__(16) u16 Ks1[128*64];     // 16KB
  __shared__ __align__(16) u16 Vt[64*128];      // 16KB [d][kv], slot^=(d&15)

  int t = threadIdx.x, lane = t&63, w = t>>6;
  int g = lane>>4, q16 = lane&15;
  int nwg = gridDim.x;
  int bid = (int)blockIdx.x;
  bid = (bid & 7)*(nwg>>3) + (bid>>3);          // XCD swizzle
  int bh = bid >> 4, qt = bid & 15;
  int b = bh >> 4, h = bh & 15;
  const u16* base = qkv + (size_t)b*1024*3072;

  bv8 qf[2];
  {
    const u16* qp = base + (size_t)((qt<<6) + (w<<4) + q16)*3072 + h*64;
    qf[0] = *(const bv8*)(qp + (g<<3));
    qf[1] = *(const bv8*)(qp + 32 + (g<<3));
  }
  f32x4 z = {0.f,0.f,0.f,0.f};
  f32x4 accO[4];
  #pragma unroll
  for(int i=0;i<4;i++) accO[i]=z;
  float m_run = -1e30f, l_run = 0.f;

  // V staging geometry: thread loads kv rows [kvr,kvr+4) x d [d0v,d0v+8)
  int d0v = (t&7)<<3;
  int c4  = t>>3;
  int sV = c4>>1, halfV = c4&1, kvr = c4<<2;
  int d15b = (t&1)<<3;

  // P-redistribution shuffle constants (validated R3/R4)
  int sel = g>>1;
  int s0l = (((g<<1)&3)<<4) | q16;
  int s1l = s0l + 16;

  bv8 v0,v1,v2,v3;
  const u16* gV0 = base + (size_t)kvr*3072 + 2048 + h*64 + d0v;

#define LDV(tl) { const u16* gV = gV0 + (size_t)(tl)*393216; \
    v0 = *(const bv8*)(gV);       v1 = *(const bv8*)(gV+3072); \
    v2 = *(const bv8*)(gV+6144);  v3 = *(const bv8*)(gV+9216); }

#define STV() { \
    _Pragma("unroll") \
    for(int i=0;i<8;i++){ \
      int d = d0v + i; \
      u32x2 val; \
      val.x = (u32)(u16)v0[i] | ((u32)(u16)v1[i]<<16); \
      val.y = (u32)(u16)v2[i] | ((u32)(u16)v3[i]<<16); \
      *(u32x2*)(Vt + d*128 + (((sV ^ (d15b+i))<<3) + (halfV<<2))) = val; \
    } }

#define KDMA(tl, buf) { \
    _Pragma("unroll") \
    for(int i=0;i<4;i++){ \
      int si = ((w<<2)+i)*64 + lane; \
      int row = si>>3; \
      int esl = (si&7) ^ (row&7); \
      gl_lds16(base + (size_t)(((tl)<<7)+row)*3072 + 1024 + h*64 + esl*8, (buf) + ((w<<2)+i)*512); \
    } }

  // prologue: K(0) DMA, V(0) regs
  KDMA(0, (u16*)Ks0);
  LDV(0);

  for(int tile=0; tile<8; ++tile){
    u16* kcur = (tile&1) ? (u16*)Ks1 : (u16*)Ks0;
    u16* knxt = (tile&1) ? (u16*)Ks0 : (u16*)Ks1;
    if(tile>0) __syncthreads();     // sync_A: all waves done reading Vt & knxt
    STV();                          // write V(tile)
    __syncthreads();                // sync_B: Vt visible; K(tile) DMA drained
    if(tile<7){
      KDMA(tile+1, knxt);           // DMA overlaps this tile's compute
      LDV(tile+1);                  // regs for next STV
    }

    // QK^T (swapped): sacc[mi] = S^T[kv=16mi+4g+r][q16], log2-domain
    f32x4 sacc[8];
    #pragma unroll
    for(int i=0;i<8;i++) sacc[i]=z;
    bv8 kf[8];
    #pragma unroll
    for(int mi=0;mi<8;mi++){
      int row = (mi<<4) + q16;
      kf[mi] = *(const bv8*)(kcur + row*64 + ((g ^ (row&7))<<3));
    }
    __builtin_amdgcn_s_setprio(1);
    #pragma unroll
    for(int mi=0;mi<8;mi++) sacc[mi] = MFMA(kf[mi], qf[0], sacc[mi]);
    __builtin_amdgcn_s_setprio(0);
    #pragma unroll
    for(int mi=0;mi<8;mi++){
      int row = (mi<<4) + q16;
      kf[mi] = *(const bv8*)(kcur + row*64 + (((4|g) ^ (row&7))<<3));
    }
    __builtin_amdgcn_s_setprio(1);
    #pragma unroll
    for(int mi=0;mi<8;mi++) sacc[mi] = MFMA(kf[mi], qf[1], sacc[mi]);
    __builtin_amdgcn_s_setprio(0);

    // online softmax in exp2 domain (per q-row = q16; replicas lane^16,^32)
    float rm = -1e30f;
    #pragma unroll
    for(int mi=0;mi<8;mi++){
      float a = fmaxf(sacc[mi][0], sacc[mi][1]);
      float c = fmaxf(sacc[mi][2], sacc[mi][3]);
      rm = fmaxf(rm, fmaxf(a, c));
    }
    rm = fmaxf(rm, __shfl_xor(rm,16,64));
    rm = fmaxf(rm, __shfl_xor(rm,32,64));
    // defer-max (T13): only rescale when max grew by >8 log2 units (x256)
    if(__any(rm > m_run + 8.0f)){
      float mnew = fmaxf(m_run, rm);
      float fac = exp2_fast(m_run - mnew);
      m_run = mnew;
      l_run *= fac;
      float fr0 = __shfl(fac, (g<<2)|0, 64);
      float fr1 = __shfl(fac, (g<<2)|1, 64);
      float fr2 = __shfl(fac, (g<<2)|2, 64);
      float fr3 = __shfl(fac, (g<<2)|3, 64);
      #pragma unroll
      for(int db=0;db<4;db++){ accO[db][0]*=fr0; accO[db][1]*=fr1; accO[db][2]*=fr2; accO[db][3]*=fr3; }
    }
    float ps = 0.f;
    #pragma unroll
    for(int mi=0;mi<8;mi++)
      #pragma unroll
      for(int r=0;r<4;r++){
        float p = exp2_fast(sacc[mi][r]-m_run);
        sacc[mi][r] = p;
        ps += p;
      }
    ps += __shfl_xor(ps,16,64);
    ps += __shfl_xor(ps,32,64);
    l_run += ps;

    // PV: pf via cvt_pk + validated shuffle network, vf from swizzled Vt
    #pragma unroll
    for(int ks=0;ks<4;ks++){
      u32 A0 = cvtpk_bf16(sacc[2*ks][0],   sacc[2*ks][1]);
      u32 A1 = cvtpk_bf16(sacc[2*ks][2],   sacc[2*ks][3]);
      u32 B0 = cvtpk_bf16(sacc[2*ks+1][0], sacc[2*ks+1][1]);
      u32 B1 = cvtpk_bf16(sacc[2*ks+1][2], sacc[2*ks+1][3]);
      u32 wA0 = (u32)__shfl((int)A0, s0l, 64), wB0 = (u32)__shfl((int)B0, s0l, 64);
      u32 wA1 = (u32)__shfl((int)A1, s0l, 64), wB1 = (u32)__shfl((int)B1, s0l, 64);
      u32 xA0 = (u32)__shfl((int)A0, s1l, 64), xB0 = (u32)__shfl((int)B0, s1l, 64);
      u32 xA1 = (u32)__shfl((int)A1, s1l, 64), xB1 = (u32)__shfl((int)B1, s1l, 64);
      union { u32 u[4]; bv8 v; } pfu;
      pfu.u[0] = sel ? wB0 : wA0;
      pfu.u[1] = sel ? wB1 : wA1;
      pfu.u[2] = sel ? xB0 : xA0;
      pfu.u[3] = sel ? xB1 : xA1;
      int fbase = ((ks<<2)|g) ^ q16;
      __builtin_amdgcn_s_setprio(1);
      #pragma unroll
      for(int db=0;db<4;db++){
        int dd = (db<<4) + q16;
        bv8 vf = *(const bv8*)(Vt + dd*128 + (fbase<<3));
        accO[db] = MFMA(pfu.v, vf, accO[db]);
      }
      __builtin_amdgcn_s_setprio(0);
    }
  }
  // epilogue
  float li0 = 1.f/__shfl(l_run, (g<<2)|0, 64);
  float li1 = 1.f/__shfl(l_run, (g<<2)|1, 64);
  float li2 = 1.f/__shfl(l_run, (g<<2)|2, 64);
  float li3 = 1.f/__shfl(l_run, (g<<2)|3, 64);
  #pragma unroll
  for(int db=0;db<4;db++){
    int qrow = (qt<<6) + (w<<4) + (g<<2);
    size_t o = (size_t)(b*1024 + qrow)*1024 + h*64 + (db<<4) + q16;
    Out[o        ] = f2bf(accO[db][0]*li0);
    Out[o + 1024 ] = f2bf(accO[db][1]*li1);
    Out[o + 2048 ] = f2bf(accO[db][2]*li2);
    Out[o + 3072 ] = f2bf(accO[db][3]*li3);
  }
#undef LDV
#undef STV
#undef KDMA
}

extern "C" void kernel_launch(void* const* d_in, const int* in_sizes, int n_in,
                              void* d_out, int out_size, void* d_ws, size_t ws_size,
                              hipStream_t stream) {
  const float* x      = (const float*)d_in[0];
  const float* cosT   = (const float*)d_in[1];
  const float* sinT   = (const float*)d_in[2];
  const float* w_qkv  = (const float*)d_in[3];
  const float* w_proj = (const float*)d_in[4];
  const float* qw     = (const float*)d_in[5];
  const float* kw     = (const float*)d_in[6];
  float* out = (float*)d_out;

  // ws layout (u16 units): xb dead after qkv GEMM -> attn aliases it.
  u16* xb     = (u16*)d_ws;                         //  8388608 elems
  u16* wqkvb  = xb     + (size_t) 8388608;          //  3145728
  u16* wprojb = wqkvb  + (size_t) 3145728;          //  1048576
  u16* qkv    = wprojb + (size_t) 1048576;          // 25165824
  u16* attn   = xb;                                 //  8388608 (alias)

  cvt_bf16<<<2048, 256, 0, stream>>>(x,      xb,     1048576);
  cvt_bf16<<<1536, 256, 0, stream>>>(w_qkv,  wqkvb,   393216);
  cvt_bf16<<< 512, 256, 0, stream>>>(w_proj, wprojb,  131072);

  gemm_bt<false><<<1536, 256, 0, stream>>>(xb, wqkvb, qkv, 8192, 3072, 1024);
  normrope<<<65536, 256, 0, stream>>>(qkv, cosT, sinT, qw, kw);
  fattn   <<<2048, 256, 0, stream>>>(qkv, attn);
  gemm_bt<true><<<512, 256, 0, stream>>>(attn, wprojb, out, 8192, 1024, 1024);
}

// Round 9
// 214.108 us; speedup vs baseline: 1.7883x; 1.1205x over previous
//
#include <hip/hip_runtime.h>
#include <hip/hip_bf16.h>
#include <stdint.h>

typedef uint16_t u16;
typedef uint32_t u32;
typedef __attribute__((ext_vector_type(8))) short bv8;    // 8 x bf16 (i16 bits), 4 VGPR
typedef __attribute__((ext_vector_type(4))) float f32x4;
typedef __attribute__((ext_vector_type(16))) float f32x16;
typedef __attribute__((ext_vector_type(2))) u32 u32x2;

#define MFMA(a,b,c)   __builtin_amdgcn_mfma_f32_16x16x32_bf16((a),(b),(c),0,0,0)
#define MFMA32(a,b,c) __builtin_amdgcn_mfma_f32_32x32x16_bf16((a),(b),(c),0,0,0)

__device__ __forceinline__ float bf2f(u16 v){ u32 x=(u32)v<<16; float f; __builtin_memcpy(&f,&x,4); return f; }
__device__ __forceinline__ u16 f2bf(float f){ u32 x; __builtin_memcpy(&x,&f,4); x += 0x7fffu + ((x>>16)&1u); return (u16)(x>>16); }
__device__ __forceinline__ u32 cvtpk_bf16(float lo, float hi){
  u32 r; asm("v_cvt_pk_bf16_f32 %0, %1, %2" : "=v"(r) : "v"(lo), "v"(hi)); return r;
}
__device__ __forceinline__ float exp2_fast(float x){
  float r; asm("v_exp_f32 %0, %1" : "=v"(r) : "v"(x)); return r;
}

__device__ __forceinline__ void gl_lds16(const u16* g, u16* l){
  __builtin_amdgcn_global_load_lds((const __attribute__((address_space(1))) u32*)g,
                                   (__attribute__((address_space(3))) u32*)l, 16, 0, 0);
}

// fp32 -> bf16 convert. n8 = elements/8.
__global__ __launch_bounds__(256) void cvt_bf16(const float* __restrict__ src, u16* __restrict__ dst, long n8){
  long i = (long)blockIdx.x*256 + threadIdx.x;
  long stride = (long)gridDim.x*256;
  for(; i<n8; i+=stride){
    f32x4 a = *(const f32x4*)(src + i*8);
    f32x4 b = *(const f32x4*)(src + i*8 + 4);
    bv8 o;
    #pragma unroll
    for(int j=0;j<4;j++) o[j]   = (short)f2bf(a[j]);
    #pragma unroll
    for(int j=0;j<4;j++) o[4+j] = (short)f2bf(b[j]);
    *(bv8*)(dst + i*8) = o;
  }
}

// ---------------------------------------------------------------------------
// C[m,n] = sum_k A[m,k] * B[n,k]   (A: MxK bf16 row-major, B: NxK bf16)
// 128x128 tile, BK=64, 4 waves, global_load_lds w/ pre-swizzled src.
// ---------------------------------------------------------------------------
template<bool OUTF32>
__global__ __launch_bounds__(256,2) void gemm_bt(const u16* __restrict__ A, const u16* __restrict__ B,
                                                 void* __restrict__ Cv, int M, int N, int K){
  __shared__ __align__(16) u16 As[128*64];
  __shared__ __align__(16) u16 Bs[128*64];
  int nwg = gridDim.x;
  int wg  = (int)blockIdx.x;
  wg = (wg & 7)*(nwg>>3) + (wg>>3);          // XCD swizzle (nwg % 8 == 0)
  int nn = N>>7;
  int tm = wg/nn, tn = wg - tm*nn;
  int rowbase = tm<<7, colbase = tn<<7;
  int t = threadIdx.x, lane = t&63, w = t>>6;
  int g = lane>>4, q16 = lane&15;
  int wr = w>>1, wc = w&1;

  f32x4 z = {0.f,0.f,0.f,0.f};
  f32x4 acc[4][4];
  #pragma unroll
  for(int i=0;i<4;i++)
    #pragma unroll
    for(int j=0;j<4;j++) acc[i][j]=z;

  for(int k0=0;k0<K;k0+=64){
    __syncthreads();
    #pragma unroll
    for(int i=0;i<4;i++){
      int s = ((w<<2)+i)*64 + lane;
      int row = s>>3;
      int ksl = (s&7) ^ (row&7);
      gl_lds16(A + (size_t)(rowbase+row)*K + k0 + ksl*8, (u16*)As + ((w<<2)+i)*512);
      gl_lds16(B + (size_t)(colbase+row)*K + k0 + ksl*8, (u16*)Bs + ((w<<2)+i)*512);
    }
    __syncthreads();
    #pragma unroll
    for(int eks=0;eks<2;eks++){
      bv8 af[4], bfr[4];
      #pragma unroll
      for(int mi=0;mi<4;mi++){
        int row = (wr<<6)+(mi<<4)+q16;
        af[mi] = *(const bv8*)(As + row*64 + ((((eks<<2)|g) ^ (row&7))<<3));
      }
      #pragma unroll
      for(int ni=0;ni<4;ni++){
        int row = (wc<<6)+(ni<<4)+q16;
        bfr[ni] = *(const bv8*)(Bs + row*64 + ((((eks<<2)|g) ^ (row&7))<<3));
      }
      #pragma unroll
      for(int mi=0;mi<4;mi++)
        #pragma unroll
        for(int ni=0;ni<4;ni++)
          acc[mi][ni] = MFMA(af[mi], bfr[ni], acc[mi][ni]);
    }
  }
  #pragma unroll
  for(int mi=0;mi<4;mi++){
    #pragma unroll
    for(int ni=0;ni<4;ni++){
      int row = rowbase + (wr<<6) + (mi<<4) + (g<<2);
      int col = colbase + (wc<<6) + (ni<<4) + q16;
      if(OUTF32){
        float* cp = (float*)Cv + (size_t)row*N + col;
        #pragma unroll
        for(int r=0;r<4;r++) cp[(size_t)r*N] = acc[mi][ni][r];
      } else {
        u16* cp = (u16*)Cv + (size_t)row*N + col;
        #pragma unroll
        for(int r=0;r<4;r++) cp[(size_t)r*N] = f2bf(acc[mi][ni][r]);
      }
    }
  }
}

// ---------------------------------------------------------------------------
// In-place RMSNorm + RoPE on q,k of qkv. One wave per row of 64.
// q rows scaled by (1/8)*log2(e): softmax scale + exp2-domain fold.
// ---------------------------------------------------------------------------
__global__ __launch_bounds__(256) void normrope(u16* __restrict__ qkv, const float* __restrict__ cosT,
                                                const float* __restrict__ sinT, const float* __restrict__ qw,
                                                const float* __restrict__ kw){
  int t = threadIdx.x, lane = t&63, wv = t>>6;
  long gid = (long)blockIdx.x*4 + wv;        // over B*L*2*H = 262144 rows
  int h = (int)(gid & 15);
  int s = (int)((gid>>4) & 1);
  long bl = gid >> 5;                        // 0..8191
  int l = (int)(bl & 1023);
  u16* p = qkv + bl*3072 + s*1024 + h*64 + lane;
  float x = bf2f(*p);
  float ss = x*x;
  #pragma unroll
  for(int m=1;m<64;m<<=1) ss += __shfl_xor(ss, m, 64);
  float nrm = rsqrtf(ss*(1.f/64.f) + 1e-6f);
  float y = x * nrm * (s ? kw[lane] : qw[lane]);
  float other = __shfl_xor(y, 32, 64);
  float rot = (lane<32)? -other : other;     // rotate_half
  int ci = l*64 + lane;
  float outv = y*cosT[ci] + rot*sinT[ci];
  *p = f2bf(s ? outv : outv*0.1803368801111437f);   // 0.125 * log2(e)
}

// ---------------------------------------------------------------------------
// Flash attention, 32x32x16 MFMA. 4 waves x 32 q-rows (BQ=128), KV tile 128
// processed as 2 sub-rounds of 64 kv. Swapped QK^T: mfma(K,Q) -> S^T with
// lane-local q-column (col=lane&31); softmax reduce = 1 shfl_xor(32).
// K double-buffered via global_load_lds DMA (validated swizzle); V^T in LDS
// (validated layout). P->PV A-frag: dual-payload shfl_xor(32) exchange.
// Defer-max (T13). Fragment maps:
//   A(32x16): row=lane&31, k=8*(lane>>5)+0..7
//   B(16x32): col=lane&31, k=8*(lane>>5)+0..7
//   C/D:      col=lane&31, row=(r&3)+8*(r>>2)+4*(lane>>5)
// ---------------------------------------------------------------------------
__global__ __launch_bounds__(256,3) void fattn(const u16* __restrict__ qkv, u16* __restrict__ Out){
  __shared__ __align__(16) u16 Ks0[128*64];     // 16KB [kv][e], slot^=(kv&7)
  __shared__ __align__(16) u16 Ks1[128*64];     // 16KB
  __shared__ __align__(16) u16 Vt[64*128];      // 16KB [d][kv], slot^=(d&15)

  int t = threadIdx.x, lane = t&63, w = t>>6;
  int ql = lane&31, h = lane>>5;
  int nwg = gridDim.x;
  int bid = (int)blockIdx.x;
  bid = (bid & 7)*(nwg>>3) + (bid>>3);          // XCD swizzle (nwg=1024)
  int bh = bid >> 3, qt = bid & 7;              // 8 q-tiles of 128 rows
  int b = bh >> 4, hd = bh & 15;
  const u16* base = qkv + (size_t)b*1024*3072;
  int Qb = (qt<<7) + (w<<5);                    // wave's 32 q-rows

  // Q B-frags: qf[s] holds Q[Qb+ql][d=16s+8h+0..7]
  bv8 qf[4];
  {
    const u16* qp = base + (size_t)(Qb+ql)*3072 + hd*64 + (h<<3);
    qf[0] = *(const bv8*)(qp);
    qf[1] = *(const bv8*)(qp+16);
    qf[2] = *(const bv8*)(qp+32);
    qf[3] = *(const bv8*)(qp+48);
  }
  f32x16 accO0, accO1;
  #pragma unroll
  for(int r=0;r<16;r++){ accO0[r]=0.f; accO1[r]=0.f; }
  float m_run = -1e30f, l_run = 0.f;

  // V staging geometry (identical to validated R8)
  int d0v = (t&7)<<3;
  int c4  = t>>3;
  int sV = c4>>1, halfV = c4&1, kvr = c4<<2;
  int d15b = (t&1)<<3;

  bv8 v0,v1,v2,v3;
  const u16* gV0 = base + (size_t)kvr*3072 + 2048 + hd*64 + d0v;

#define LDV(tl) { const u16* gV = gV0 + (size_t)(tl)*393216; \
    v0 = *(const bv8*)(gV);       v1 = *(const bv8*)(gV+3072); \
    v2 = *(const bv8*)(gV+6144);  v3 = *(const bv8*)(gV+9216); }

#define STV() { \
    _Pragma("unroll") \
    for(int i=0;i<8;i++){ \
      int d = d0v + i; \
      u32x2 val; \
      val.x = (u32)(u16)v0[i] | ((u32)(u16)v1[i]<<16); \
      val.y = (u32)(u16)v2[i] | ((u32)(u16)v3[i]<<16); \
      *(u32x2*)(Vt + d*128 + (((sV ^ (d15b+i))<<3) + (halfV<<2))) = val; \
    } }

#define KDMA(tl, buf) { \
    _Pragma("unroll") \
    for(int i=0;i<4;i++){ \
      int si = ((w<<2)+i)*64 + lane; \
      int row = si>>3; \
      int esl = (si&7) ^ (row&7); \
      gl_lds16(base + (size_t)(((tl)<<7)+row)*3072 + 1024 + hd*64 + esl*8, (buf) + ((w<<2)+i)*512); \
    } }

  // prologue: K(0) DMA, V(0) regs
  KDMA(0, (u16*)Ks0);
  LDV(0);

  for(int tile=0; tile<8; ++tile){
    u16* kcur = (tile&1) ? (u16*)Ks1 : (u16*)Ks0;
    u16* knxt = (tile&1) ? (u16*)Ks0 : (u16*)Ks1;
    if(tile>0) __syncthreads();     // all waves done reading Vt & knxt
    STV();                          // write V(tile)
    __syncthreads();                // Vt visible; K(tile) DMA drained
    if(tile<7){
      KDMA(tile+1, knxt);           // DMA overlaps this tile's compute
      LDV(tile+1);                  // regs for next STV
    }

    #pragma unroll
    for(int sub=0; sub<2; ++sub){
      // ---- QK^T: S^T[kv 64][q 32] over kv = 128*tile + 64*sub + ...
      f32x16 s0, s1;
      #pragma unroll
      for(int r=0;r<16;r++){ s0[r]=0.f; s1[r]=0.f; }
      int rowA = (sub<<6) + ql;             // kv subtile 2sub
      int rowB = rowA + 32;                 // kv subtile 2sub+1
      __builtin_amdgcn_s_setprio(1);
      #pragma unroll
      for(int s=0;s<4;s++){
        bv8 ka = *(const bv8*)(kcur + rowA*64 + ((((s<<1)|h) ^ (rowA&7))<<3));
        bv8 kb = *(const bv8*)(kcur + rowB*64 + ((((s<<1)|h) ^ (rowB&7))<<3));
        s0 = MFMA32(ka, qf[s], s0);
        s1 = MFMA32(kb, qf[s], s1);
      }
      __builtin_amdgcn_s_setprio(0);

      // ---- online softmax (lane owns q-col ql; partner at lane^32)
      float rm = -1e30f;
      #pragma unroll
      for(int r=0;r<16;r++){ rm = fmaxf(rm, fmaxf(s0[r], s1[r])); }
      rm = fmaxf(rm, __shfl_xor(rm, 32, 64));
      if(__any(rm > m_run + 8.0f)){         // defer-max
        float mnew = fmaxf(m_run, rm);
        float fac = exp2_fast(m_run - mnew);
        m_run = mnew;
        l_run *= fac;
        #pragma unroll
        for(int r=0;r<16;r++){
          int qs = (r&3) + ((r>>2)<<3) + (h<<2);
          float fr = __shfl(fac, qs, 64);
          accO0[r] *= fr; accO1[r] *= fr;
        }
      }
      float ps = 0.f;
      #pragma unroll
      for(int r=0;r<16;r++){
        float p0 = exp2_fast(s0[r]-m_run); s0[r] = p0;
        float p1 = exp2_fast(s1[r]-m_run); s1[r] = p1;
        ps += p0 + p1;
      }
      ps += __shfl_xor(ps, 32, 64);
      l_run += ps;

      // ---- PV: O[32q][64d] += P[32q][64kv] * V[64kv][64d]
      int dsw = ql & 15;
      #pragma unroll
      for(int tt=0; tt<4; ++tt){
        // A-frag kv16-slice tt: lane needs kv32' = 16*(tt&1)+8h+{0..7} of
        // subtile (tt<2 ? s0 : s1). Own regs hold kv32' = (r&3)+8*(r>>2)+4h.
        int b0 = (tt&1)<<1;                 // reg-block base (b index)
        float a0,a1,a2,a3,b4,b5,b6,b7;
        if(tt<2){ a0=s0[4*b0+0]; a1=s0[4*b0+1]; a2=s0[4*b0+2]; a3=s0[4*b0+3];
                  b4=s0[4*b0+4]; b5=s0[4*b0+5]; b6=s0[4*b0+6]; b7=s0[4*b0+7]; }
        else    { a0=s1[4*b0+0]; a1=s1[4*b0+1]; a2=s1[4*b0+2]; a3=s1[4*b0+3];
                  b4=s1[4*b0+4]; b5=s1[4*b0+5]; b6=s1[4*b0+6]; b7=s1[4*b0+7]; }
        u32 Wlo0 = cvtpk_bf16(a0,a1), Wlo1 = cvtpk_bf16(a2,a3);   // kv 8b0+4h+{0..3}
        u32 Whi0 = cvtpk_bf16(b4,b5), Whi1 = cvtpk_bf16(b6,b7);   // kv 8b0+8+4h+{0..3}
        // dual-payload exchange: send the family the partner needs
        u32 X0 = h ? Wlo0 : Whi0;
        u32 X1 = h ? Wlo1 : Whi1;
        u32 x0 = (u32)__shfl_xor((int)X0, 32, 64);
        u32 x1 = (u32)__shfl_xor((int)X1, 32, 64);
        union { u32 u[4]; bv8 v; } pf;
        pf.u[0] = h ? x0 : Wlo0;
        pf.u[1] = h ? x1 : Wlo1;
        pf.u[2] = h ? Whi0 : x0;
        pf.u[3] = h ? Whi1 : x1;
        int vslot = ((sub<<3)+(tt<<1)+h) ^ dsw;
        bv8 vf0 = *(const bv8*)(Vt + ql*128 + (vslot<<3));
        bv8 vf1 = *(const bv8*)(Vt + (32+ql)*128 + (vslot<<3));
        __builtin_amdgcn_s_setprio(1);
        accO0 = MFMA32(pf.v, vf0, accO0);
        accO1 = MFMA32(pf.v, vf1, accO1);
        __builtin_amdgcn_s_setprio(0);
      }
    }
  }
  // ---- epilogue: divide by l (per-q broadcast) and store
  float linv = 1.f/l_run;
  #pragma unroll
  for(int r=0;r<16;r++){
    int qs = (r&3) + ((r>>2)<<3) + (h<<2);
    float li = __shfl(linv, qs, 64);
    size_t o = (size_t)(b*1024 + Qb + qs)*1024 + hd*64 + ql;
    Out[o]      = f2bf(accO0[r]*li);
    Out[o + 32] = f2bf(accO1[r]*li);
  }
#undef LDV
#undef STV
#undef KDMA
}

extern "C" void kernel_launch(void* const* d_in, const int* in_sizes, int n_in,
                              void* d_out, int out_size, void* d_ws, size_t ws_size,
                              hipStream_t stream) {
  const float* x      = (const float*)d_in[0];
  const float* cosT   = (const float*)d_in[1];
  const float* sinT   = (const float*)d_in[2];
  const float* w_qkv  = (const float*)d_in[3];
  const float* w_proj = (const float*)d_in[4];
  const float* qw     = (const float*)d_in[5];
  const float* kw     = (const float*)d_in[6];
  float* out = (float*)d_out;

  // ws layout (u16 units): xb dead after qkv GEMM -> attn aliases it.
  u16* xb     = (u16*)d_ws;                         //  8388608 elems
  u16* wqkvb  = xb     + (size_t) 8388608;          //  3145728
  u16* wprojb = wqkvb  + (size_t) 3145728;          //  1048576
  u16* qkv    = wprojb + (size_t) 1048576;          // 25165824
  u16* attn   = xb;                                 //  8388608 (alias)

  cvt_bf16<<<2048, 256, 0, stream>>>(x,      xb,     1048576);
  cvt_bf16<<<1536, 256, 0, stream>>>(w_qkv,  wqkvb,   393216);
  cvt_bf16<<< 512, 256, 0, stream>>>(w_proj, wprojb,  131072);

  gemm_bt<false><<<1536, 256, 0, stream>>>(xb, wqkvb, qkv, 8192, 3072, 1024);
  normrope<<<65536, 256, 0, stream>>>(qkv, cosT, sinT, qw, kw);
  fattn   <<<1024, 256, 0, stream>>>(qkv, attn);
  gemm_bt<true><<<512, 256, 0, stream>>>(attn, wprojb, out, 8192, 1024, 1024);
}